// Round 5
// baseline (275.703 us; speedup 1.0000x reference)
//
#include <hip/hip_runtime.h>

// BinaryMatchAttention: out[b,d] = sum_s prod_k(1-|x[b,s,96+k]-qbit[k]|) * x[b,s,d], d<96
// x: (8, 32768, 128) fp32, query_addr: int scalar, out: (8, 96) fp32.
//
// R5 = MEASUREMENT PROBE. Identical kernels to R4, but stage1 is launched 5x
// (idempotent: each rep rewrites the same partials). The marginal dur_us per
// rep measures stage1's true duration, which is hidden below the harness's
// 77us poison fills in the rocprof top-5. Interpretation:
//   dur ~250-270  -> stage1 ~15-20us (BW-bound, harness floor dominates)
//   dur ~370-430  -> stage1 ~45-60us (latency/structure-bound, rewrite next)

constexpr int B = 8;
constexpr int S = 32768;
constexpr int D4 = 32;            // float4 columns per row (128 floats)
constexpr int VAL4 = 24;          // value float4 columns (96 floats)
constexpr int BLOCKS_PER_B = 256;
constexpr int SPB = S / BLOCKS_PER_B;          // 128 rows per block
constexpr int ROWS_PER_ITER = 32;              // phase 2: 256 thr / 8 lanes-per-row
constexpr int P2_ITERS = SPB / ROWS_PER_ITER;  // 4
constexpr int REPS = 5;

__global__ __launch_bounds__(256)
void bma_stage1(const float* __restrict__ x, const int* __restrict__ qaddr,
                float* __restrict__ partial) {
    const int t  = threadIdx.x;
    const int b  = blockIdx.x / BLOCKS_PER_B;
    const int s0 = (blockIdx.x % BLOCKS_PER_B) * SPB;

    const float4* __restrict__ xb =
        reinterpret_cast<const float4*>(x) + (long)b * S * D4;

    __shared__ float  wlds[SPB];            // per-row weights
    __shared__ float4 red[32][VAL4 + 1];    // +1 float4 pad vs bank aliasing

    // ---- phase 1: weights for all 128 rows (one pass, 2 key-float4s/thread)
    {
        const unsigned qa  = (unsigned)qaddr[0];
        const int row  = t >> 1;            // 0..127
        const int h    = t & 1;             // which 8-bit half of the key
        const long rb  = (long)(s0 + row) * D4;
        const float4 k0 = xb[rb + 24 + 2 * h];
        const float4 k1 = xb[rb + 25 + 2 * h];
        const int base = h * 8;
        float p = 1.0f;
        p *= 1.0f - fabsf(k0.x - (float)((qa >> (base + 0)) & 1u));
        p *= 1.0f - fabsf(k0.y - (float)((qa >> (base + 1)) & 1u));
        p *= 1.0f - fabsf(k0.z - (float)((qa >> (base + 2)) & 1u));
        p *= 1.0f - fabsf(k0.w - (float)((qa >> (base + 3)) & 1u));
        p *= 1.0f - fabsf(k1.x - (float)((qa >> (base + 4)) & 1u));
        p *= 1.0f - fabsf(k1.y - (float)((qa >> (base + 5)) & 1u));
        p *= 1.0f - fabsf(k1.z - (float)((qa >> (base + 6)) & 1u));
        p *= 1.0f - fabsf(k1.w - (float)((qa >> (base + 7)) & 1u));
        p *= __shfl_xor(p, 1);              // combine the two halves (same wave)
        if (h == 0) wlds[row] = p;
    }
    __syncthreads();

    // ---- phase 2: pure streaming, no cross-lane ops.
    const int f  = t & 7;
    const int rg = t >> 3;                  // 0..31
    float4 a0 = make_float4(0.f, 0.f, 0.f, 0.f);
    float4 a1 = a0, a2 = a0;

    #pragma unroll
    for (int i = 0; i < P2_ITERS; ++i) {
        const int  row  = i * ROWS_PER_ITER + rg;
        const long base = (long)(s0 + row) * D4;
        const float4 v0 = xb[base + f];
        const float4 v1 = xb[base + f + 8];
        const float4 v2 = xb[base + f + 16];
        const float  w  = wlds[row];        // 8-lane broadcast, conflict-free
        a0.x = fmaf(w, v0.x, a0.x); a0.y = fmaf(w, v0.y, a0.y);
        a0.z = fmaf(w, v0.z, a0.z); a0.w = fmaf(w, v0.w, a0.w);
        a1.x = fmaf(w, v1.x, a1.x); a1.y = fmaf(w, v1.y, a1.y);
        a1.z = fmaf(w, v1.z, a1.z); a1.w = fmaf(w, v1.w, a1.w);
        a2.x = fmaf(w, v2.x, a2.x); a2.y = fmaf(w, v2.y, a2.y);
        a2.z = fmaf(w, v2.z, a2.z); a2.w = fmaf(w, v2.w, a2.w);
    }

    red[rg][f]      = a0;
    red[rg][f + 8]  = a1;
    red[rg][f + 16] = a2;
    __syncthreads();

    if (t < VAL4) {
        float4 sum = make_float4(0.f, 0.f, 0.f, 0.f);
        #pragma unroll 8
        for (int g = 0; g < 32; ++g) {
            const float4 o = red[g][t];
            sum.x += o.x; sum.y += o.y; sum.z += o.z; sum.w += o.w;
        }
        reinterpret_cast<float4*>(partial)[(long)blockIdx.x * VAL4 + t] = sum;
    }
}

// partial: [B*BLOCKS_PER_B][96] floats -> out: [B][96].
__global__ __launch_bounds__(256)
void bma_stage2(const float* __restrict__ partial, float* __restrict__ out) {
    const int t  = threadIdx.x;
    const int c  = t & 31;   // float4 column (0..23 active)
    const int rg = t >> 5;   // chunk group 0..7
    const int b  = blockIdx.x;

    const float4* __restrict__ pp =
        reinterpret_cast<const float4*>(partial) + (long)b * BLOCKS_PER_B * VAL4;

    float4 acc = make_float4(0.f, 0.f, 0.f, 0.f);
    if (c < VAL4) {
        #pragma unroll 4
        for (int chunk = rg; chunk < BLOCKS_PER_B; chunk += 8) {
            const float4 v = pp[(long)chunk * VAL4 + c];
            acc.x += v.x; acc.y += v.y; acc.z += v.z; acc.w += v.w;
        }
    }

    __shared__ float4 red[256];
    red[t] = acc;
    __syncthreads();
    if (t < VAL4) {
        float4 sum = red[t];
        #pragma unroll
        for (int g = 1; g < 8; ++g) {
            const float4 o = red[t + 32 * g];
            sum.x += o.x; sum.y += o.y; sum.z += o.z; sum.w += o.w;
        }
        reinterpret_cast<float4*>(out)[(long)b * VAL4 + t] = sum;
    }
}

extern "C" void kernel_launch(void* const* d_in, const int* in_sizes, int n_in,
                              void* d_out, int out_size, void* d_ws, size_t ws_size,
                              hipStream_t stream) {
    const float* x   = (const float*)d_in[0];
    const int*   qa  = (const int*)d_in[1];
    float*       out = (float*)d_out;
    float*       ws  = (float*)d_ws;   // partials: B*256*96*4 = 768 KiB

    // PROBE: 5 idempotent stage1 launches; marginal cost per launch = stage1 time.
    for (int r = 0; r < REPS; ++r)
        bma_stage1<<<dim3(B * BLOCKS_PER_B), dim3(256), 0, stream>>>(x, qa, ws);
    bma_stage2<<<dim3(B), dim3(256), 0, stream>>>(ws, out);
}

// Round 6
// 195.326 us; speedup vs baseline: 1.4115x; 1.4115x over previous
//
#include <hip/hip_runtime.h>

// BinaryMatchAttention: out[b,d] = sum_s prod_k(1-|x[b,s,96+k]-qbit[k]|) * x[b,s,d], d<96
// x: (8, 32768, 128) fp32, query_addr: int scalar, out: (8, 96) fp32.
//
// Final structure (measured via the R5 5x-launch probe):
//   stage1 ~21us (114.3 MB fetched, ~15% over pure-HBM ideal of ~18us),
//   stage2 ~3us, harness fixed floor ~168us (512MiB ws re-poison = 77us, etc).
// Stage 1 per block = 128 rows: phase 1 computes all row weights into LDS
// (the only cross-lane ops); phase 2 streams values (cols 0..95) with full
// coalescing and independent loads; cols 112..127 are never touched.
// Stage 2 reduces 256 partials/batch. No atomics, no device-scope fences.

constexpr int B = 8;
constexpr int S = 32768;
constexpr int D4 = 32;            // float4 columns per row (128 floats)
constexpr int VAL4 = 24;          // value float4 columns (96 floats)
constexpr int BLOCKS_PER_B = 256;
constexpr int SPB = S / BLOCKS_PER_B;          // 128 rows per block
constexpr int ROWS_PER_ITER = 32;              // phase 2: 256 thr / 8 lanes-per-row
constexpr int P2_ITERS = SPB / ROWS_PER_ITER;  // 4

__global__ __launch_bounds__(256)
void bma_stage1(const float* __restrict__ x, const int* __restrict__ qaddr,
                float* __restrict__ partial) {
    const int t  = threadIdx.x;
    const int b  = blockIdx.x / BLOCKS_PER_B;
    const int s0 = (blockIdx.x % BLOCKS_PER_B) * SPB;

    const float4* __restrict__ xb =
        reinterpret_cast<const float4*>(x) + (long)b * S * D4;

    __shared__ float  wlds[SPB];            // per-row weights
    __shared__ float4 red[32][VAL4 + 1];    // +1 float4 pad vs bank aliasing

    // ---- phase 1: weights for all 128 rows (one pass, 2 key-float4s/thread)
    {
        const unsigned qa  = (unsigned)qaddr[0];
        const int row  = t >> 1;            // 0..127
        const int h    = t & 1;             // which 8-bit half of the key
        const long rb  = (long)(s0 + row) * D4;
        const float4 k0 = xb[rb + 24 + 2 * h];
        const float4 k1 = xb[rb + 25 + 2 * h];
        const int base = h * 8;
        float p = 1.0f;
        p *= 1.0f - fabsf(k0.x - (float)((qa >> (base + 0)) & 1u));
        p *= 1.0f - fabsf(k0.y - (float)((qa >> (base + 1)) & 1u));
        p *= 1.0f - fabsf(k0.z - (float)((qa >> (base + 2)) & 1u));
        p *= 1.0f - fabsf(k0.w - (float)((qa >> (base + 3)) & 1u));
        p *= 1.0f - fabsf(k1.x - (float)((qa >> (base + 4)) & 1u));
        p *= 1.0f - fabsf(k1.y - (float)((qa >> (base + 5)) & 1u));
        p *= 1.0f - fabsf(k1.z - (float)((qa >> (base + 6)) & 1u));
        p *= 1.0f - fabsf(k1.w - (float)((qa >> (base + 7)) & 1u));
        p *= __shfl_xor(p, 1);              // combine the two halves (same wave)
        if (h == 0) wlds[row] = p;
    }
    __syncthreads();

    // ---- phase 2: pure streaming, no cross-lane ops.
    // thread (rg = t>>3, f = t&7) reads rows rg, rg+32, rg+64, rg+96;
    // per row: 3 float4 loads at cols f, f+8, f+16 (8 lanes = one 128B line).
    const int f  = t & 7;
    const int rg = t >> 3;                  // 0..31
    float4 a0 = make_float4(0.f, 0.f, 0.f, 0.f);
    float4 a1 = a0, a2 = a0;

    #pragma unroll
    for (int i = 0; i < P2_ITERS; ++i) {
        const int  row  = i * ROWS_PER_ITER + rg;
        const long base = (long)(s0 + row) * D4;
        const float4 v0 = xb[base + f];
        const float4 v1 = xb[base + f + 8];
        const float4 v2 = xb[base + f + 16];
        const float  w  = wlds[row];        // 8-lane broadcast, conflict-free
        a0.x = fmaf(w, v0.x, a0.x); a0.y = fmaf(w, v0.y, a0.y);
        a0.z = fmaf(w, v0.z, a0.z); a0.w = fmaf(w, v0.w, a0.w);
        a1.x = fmaf(w, v1.x, a1.x); a1.y = fmaf(w, v1.y, a1.y);
        a1.z = fmaf(w, v1.z, a1.z); a1.w = fmaf(w, v1.w, a1.w);
        a2.x = fmaf(w, v2.x, a2.x); a2.y = fmaf(w, v2.y, a2.y);
        a2.z = fmaf(w, v2.z, a2.z); a2.w = fmaf(w, v2.w, a2.w);
    }

    red[rg][f]      = a0;
    red[rg][f + 8]  = a1;
    red[rg][f + 16] = a2;
    __syncthreads();

    if (t < VAL4) {
        float4 sum = make_float4(0.f, 0.f, 0.f, 0.f);
        #pragma unroll 8
        for (int g = 0; g < 32; ++g) {
            const float4 o = red[g][t];
            sum.x += o.x; sum.y += o.y; sum.z += o.z; sum.w += o.w;
        }
        reinterpret_cast<float4*>(partial)[(long)blockIdx.x * VAL4 + t] = sum;
    }
}

// partial: [B*BLOCKS_PER_B][96] floats -> out: [B][96].
__global__ __launch_bounds__(256)
void bma_stage2(const float* __restrict__ partial, float* __restrict__ out) {
    const int t  = threadIdx.x;
    const int c  = t & 31;   // float4 column (0..23 active)
    const int rg = t >> 5;   // chunk group 0..7
    const int b  = blockIdx.x;

    const float4* __restrict__ pp =
        reinterpret_cast<const float4*>(partial) + (long)b * BLOCKS_PER_B * VAL4;

    float4 acc = make_float4(0.f, 0.f, 0.f, 0.f);
    if (c < VAL4) {
        #pragma unroll 4
        for (int chunk = rg; chunk < BLOCKS_PER_B; chunk += 8) {
            const float4 v = pp[(long)chunk * VAL4 + c];
            acc.x += v.x; acc.y += v.y; acc.z += v.z; acc.w += v.w;
        }
    }

    __shared__ float4 red[256];
    red[t] = acc;
    __syncthreads();
    if (t < VAL4) {
        float4 sum = red[t];
        #pragma unroll
        for (int g = 1; g < 8; ++g) {
            const float4 o = red[t + 32 * g];
            sum.x += o.x; sum.y += o.y; sum.z += o.z; sum.w += o.w;
        }
        reinterpret_cast<float4*>(out)[(long)b * VAL4 + t] = sum;
    }
}

extern "C" void kernel_launch(void* const* d_in, const int* in_sizes, int n_in,
                              void* d_out, int out_size, void* d_ws, size_t ws_size,
                              hipStream_t stream) {
    const float* x   = (const float*)d_in[0];
    const int*   qa  = (const int*)d_in[1];
    float*       out = (float*)d_out;
    float*       ws  = (float*)d_ws;   // partials: B*256*96*4 = 768 KiB

    bma_stage1<<<dim3(B * BLOCKS_PER_B), dim3(256), 0, stream>>>(x, qa, ws);
    bma_stage2<<<dim3(B), dim3(256), 0, stream>>>(ws, out);
}